// Round 15
// baseline (273.226 us; speedup 1.0000x reference)
//
#include <hip/hip_runtime.h>
#include <hip/hip_fp16.h>

#define NEG_SLOPE_F 0.2f

typedef __attribute__((ext_vector_type(8))) short bf16x8;
typedef __attribute__((ext_vector_type(4))) float f32x4;

__device__ __forceinline__ float lrelu(float v) { return v > 0.0f ? v : NEG_SLOPE_F * v; }

__device__ __forceinline__ unsigned short f2bf(float f) {
  unsigned int u = __float_as_uint(f);
  u += 0x7FFFu + ((u >> 16) & 1u);  // round-to-nearest-even
  return (unsigned short)(u >> 16);
}
__device__ __forceinline__ float bf2f(unsigned short s) {
  return __uint_as_float(((unsigned int)s) << 16);
}

// ---------------- CSR construction ----------------
__global__ void hist_kernel(const int* __restrict__ dst, int* __restrict__ cnt, int E) {
  for (int i = blockIdx.x * blockDim.x + threadIdx.x; i < E; i += gridDim.x * blockDim.x)
    atomicAdd(&cnt[dst[i]], 1);
}

__global__ void chunk_sum_kernel(const int* __restrict__ cnt, int* __restrict__ bsum, int Nn) {
  __shared__ int sm[256];
  int t = threadIdx.x;
  int i = blockIdx.x * 256 + t;
  sm[t] = (i < Nn) ? cnt[i] : 0;
  __syncthreads();
  for (int off = 128; off > 0; off >>= 1) {
    if (t < off) sm[t] += sm[t + off];
    __syncthreads();
  }
  if (t == 0) bsum[blockIdx.x] = sm[0];
}

__global__ void scan_base_kernel(const int* __restrict__ bsum, int* __restrict__ bbase,
                                 int* __restrict__ offs, int nchunk, int Nn) {
  __shared__ int sm[256];
  int t = threadIdx.x;
  int v = (t < nchunk) ? bsum[t] : 0;
  sm[t] = v;
  __syncthreads();
  for (int off = 1; off < 256; off <<= 1) {
    int x = (t >= off) ? sm[t - off] : 0;
    __syncthreads();
    sm[t] += x;
    __syncthreads();
  }
  if (t < nchunk) bbase[t] = sm[t] - v;  // exclusive base for chunk t
  if (t == 255) offs[Nn] = sm[255];      // grand total
}

__global__ void chunk_scan_kernel(const int* __restrict__ cnt, const int* __restrict__ bbase,
                                  int* __restrict__ offs, int* __restrict__ cur, int Nn) {
  __shared__ int sm[256];
  int t = threadIdx.x;
  int i = blockIdx.x * 256 + t;
  int v = (i < Nn) ? cnt[i] : 0;
  sm[t] = v;
  __syncthreads();
  for (int off = 1; off < 256; off <<= 1) {
    int x = (t >= off) ? sm[t - off] : 0;
    __syncthreads();
    sm[t] += x;
    __syncthreads();
  }
  if (i < Nn) {
    int ex = bbase[blockIdx.x] + sm[t] - v;
    offs[i] = ex;
    cur[i] = ex;
  }
}

__global__ void scatter_kernel(const int* __restrict__ src, const int* __restrict__ dst,
                               int* __restrict__ cur, int* __restrict__ csr, int E) {
  for (int i = blockIdx.x * blockDim.x + threadIdx.x; i < E; i += gridDim.x * blockDim.x) {
    int p = atomicAdd(&cur[dst[i]], 1);
    csr[p] = src[i];
  }
}

// ---------------- operand prep (bf16 activations, hi+lo weights) ------------
// x[rows,256] fp32 -> A[rowsPad,256] bf16 (hi only); pad rows zero-filled.
__global__ void split_x_kernel(const float* __restrict__ src, unsigned short* __restrict__ dst,
                               int rows, int rowsPad) {
  int total = rowsPad * 64;  // groups of 4 elems
  for (int i = blockIdx.x * blockDim.x + threadIdx.x; i < total; i += gridDim.x * blockDim.x) {
    int r = i >> 6, c = (i & 63) * 4;
    short4 hv;
    if (r < rows) {
      float4 v = *(const float4*)(src + (size_t)r * 256 + c);
      hv = make_short4((short)f2bf(v.x), (short)f2bf(v.y),
                       (short)f2bf(v.z), (short)f2bf(v.w));
    } else {
      hv = make_short4(0, 0, 0, 0);
    }
    *(short4*)(dst + (size_t)r * 256 + c) = hv;
  }
}

// Both weight matrices -> Bt[N][512]: k'<256 hi, 256..511 lo (weight residual).
__global__ void build_bt_kernel(const float* __restrict__ W1, const float* __restrict__ W2,
                                unsigned short* __restrict__ Bt1, unsigned short* __restrict__ Bt2) {
  int i = blockIdx.x * blockDim.x + threadIdx.x;
  const int total1 = 256 * 256;
  const int total2 = 128 * 256;
  if (i < total1) {
    int n = i >> 8, k = i & 255;
    float v = W1[(size_t)k * 256 + n];
    unsigned short hi = f2bf(v);
    unsigned short lo = f2bf(v - bf2f(hi));
    Bt1[(size_t)n * 512 + k] = hi;
    Bt1[(size_t)n * 512 + 256 + k] = lo;
  } else if (i < total1 + total2) {
    int j = i - total1;
    int n = j >> 8, k = j & 255;
    float v = W2[(size_t)k * 128 + n];
    unsigned short hi = f2bf(v);
    unsigned short lo = f2bf(v - bf2f(hi));
    Bt2[(size_t)n * 512 + k] = hi;
    Bt2[(size_t)n * 512 + 256 + k] = lo;
  }
}

// ---------------- bf16 MFMA GEMM (C = A x (B_hi+B_lo)), single-pass A -------
// A[Mpad,256] bf16, Bt[N,512] (hi|lo). 8 K-tiles of 32; per tile stage A once
// plus BOTH B parts, two MFMA sets per barrier pair. Fused logit epilogue.
// DLOG = log2(head dim): 6 (L1, D=64), 5 (L2, D=32).
template <int DLOG>
__global__ __launch_bounds__(256) void gemm_fused(const unsigned short* __restrict__ A,
                                                  const unsigned short* __restrict__ Bt,
                                                  const float* __restrict__ a_src,
                                                  const float* __restrict__ a_dst,
                                                  __half* __restrict__ Ch,
                                                  float* __restrict__ al_s,
                                                  float* __restrict__ al_d,
                                                  int M, int N) {
  __shared__ unsigned short As[128 * 32];
  __shared__ unsigned short Bs[2 * 128 * 32];  // [part][row][slot]
  const int tid = threadIdx.x;
  const int lane = tid & 63;
  const int wave = tid >> 6;
  const int wm = (wave >> 1) * 64;
  const int wn = (wave & 1) * 64;
  const int bm = blockIdx.y * 128;
  const int bn = blockIdx.x * 128;
  const int fr = lane & 15;
  const int q = lane >> 4;
  const int srow = tid >> 2;   // 0..63
  const int sslot = tid & 3;
  f32x4 acc[4][4] = {};
  for (int kt = 0; kt < 8; ++kt) {
    const int kk = kt * 32;
#pragma unroll
    for (int i = 0; i < 2; ++i) {
      int r = i * 64 + srow;
      int sl = sslot ^ (r & 3);
      __builtin_amdgcn_global_load_lds(
          (const __attribute__((address_space(1))) unsigned int*)(A + (size_t)(bm + r) * 256 + kk + sl * 8),
          (__attribute__((address_space(3))) unsigned int*)((char*)As + i * 4096 + wave * 1024),
          16, 0, 0);
    }
#pragma unroll
    for (int pp = 0; pp < 2; ++pp) {
#pragma unroll
      for (int i = 0; i < 2; ++i) {
        int r = i * 64 + srow;
        int sl = sslot ^ (r & 3);
        __builtin_amdgcn_global_load_lds(
            (const __attribute__((address_space(1))) unsigned int*)(Bt + (size_t)(bn + r) * 512 + pp * 256 + kk + sl * 8),
            (__attribute__((address_space(3))) unsigned int*)((char*)Bs + pp * 8192 + i * 4096 + wave * 1024),
            16, 0, 0);
      }
    }
    __syncthreads();  // drains vmcnt -> LDS tiles ready
    bf16x8 af[4], bh[4], bl[4];
#pragma unroll
    for (int mi = 0; mi < 4; ++mi) {
      int r = wm + mi * 16 + fr;
      af[mi] = *(const bf16x8*)(As + r * 32 + (q ^ (r & 3)) * 8);
    }
#pragma unroll
    for (int ni = 0; ni < 4; ++ni) {
      int r = wn + ni * 16 + fr;
      bh[ni] = *(const bf16x8*)(Bs + r * 32 + (q ^ (r & 3)) * 8);
      bl[ni] = *(const bf16x8*)(Bs + 4096 + r * 32 + (q ^ (r & 3)) * 8);
    }
#pragma unroll
    for (int mi = 0; mi < 4; ++mi)
#pragma unroll
      for (int ni = 0; ni < 4; ++ni) {
        acc[mi][ni] = __builtin_amdgcn_mfma_f32_16x16x32_bf16(af[mi], bh[ni], acc[mi][ni], 0, 0, 0);
        acc[mi][ni] = __builtin_amdgcn_mfma_f32_16x16x32_bf16(af[mi], bl[ni], acc[mi][ni], 0, 0, 0);
      }
    __syncthreads();  // compute done before next-stage overwrite
  }
  // attention vectors for this thread's 4 columns (flat index == col)
  float asv[4], adv[4];
#pragma unroll
  for (int ni = 0; ni < 4; ++ni) {
    int colg = bn + wn + ni * 16 + fr;
    asv[ni] = a_src[colg];
    adv[ni] = a_dst[colg];
  }
  const int hb = (bn + wn) >> DLOG;
#pragma unroll
  for (int mi = 0; mi < 4; ++mi) {
#pragma unroll
    for (int r = 0; r < 4; ++r) {
      int row = bm + wm + mi * 16 + q * 4 + r;
      float ps0 = 0.f, pd0 = 0.f, ps1 = 0.f, pd1 = 0.f;
#pragma unroll
      for (int ni = 0; ni < 4; ++ni) {
        float v = acc[mi][ni][r];
        if (DLOG == 6 || ni < 2) { ps0 += v * asv[ni]; pd0 += v * adv[ni]; }
        else                     { ps1 += v * asv[ni]; pd1 += v * adv[ni]; }
      }
#pragma unroll
      for (int off = 1; off < 16; off <<= 1) {
        ps0 += __shfl_xor(ps0, off, 64);
        pd0 += __shfl_xor(pd0, off, 64);
        if (DLOG == 5) {
          ps1 += __shfl_xor(ps1, off, 64);
          pd1 += __shfl_xor(pd1, off, 64);
        }
      }
      if (fr == 0 && row < M) {
        al_s[row * 4 + hb] = ps0;
        al_d[row * 4 + hb] = pd0;
        if (DLOG == 5) {
          al_s[row * 4 + hb + 1] = ps1;
          al_d[row * 4 + hb + 1] = pd1;
        }
      }
    }
  }
  // fp16 feature store
#pragma unroll
  for (int mi = 0; mi < 4; ++mi) {
#pragma unroll
    for (int ni = 0; ni < 4; ++ni) {
      int col = bn + wn + ni * 16 + fr;
#pragma unroll
      for (int r = 0; r < 4; ++r) {
        int row = bm + wm + mi * 16 + q * 4 + r;
        if (row < M) Ch[(size_t)row * N + col] = __float2half(acc[mi][ni][r]);
      }
    }
  }
}

// ---------------- layer-1 aggregation: 2 nodes/wave, batch-8 gathers --------
// 32 lanes per node; lane l owns channels l*8..l*8+7 (head l>>3).
__global__ __launch_bounds__(256) void gat_agg1(const __half* __restrict__ hg,
                                                const float* __restrict__ als,
                                                const float* __restrict__ aldv,
                                                const int* __restrict__ offs,
                                                const int* __restrict__ csr,
                                                const float* __restrict__ b1,
                                                unsigned short* __restrict__ A2, int Nn) {
  int node = blockIdx.x * 8 + (threadIdx.x >> 5);
  if (node >= Nn) return;
  int l = threadIdx.x & 31;
  int head = l >> 3;
  float ald = aldv[node * 4 + head];
  float p = __expf(lrelu(als[node * 4 + head] + ald));  // self-loop
  float s = p;
  float acc[8];
  {
    float4 raw = *(const float4*)(hg + (size_t)node * 256 + l * 8);
    const __half2* hp = (const __half2*)&raw;
#pragma unroll
    for (int i = 0; i < 4; ++i) {
      float2 f = __half22float2(hp[i]);
      acc[2 * i] = p * f.x;
      acc[2 * i + 1] = p * f.y;
    }
  }
  int beg = offs[node], end = offs[node + 1];
  int k = beg;
  for (; k + 7 < end; k += 8) {
    int t0 = csr[k],     t1 = csr[k + 1], t2 = csr[k + 2], t3 = csr[k + 3];
    int t4 = csr[k + 4], t5 = csr[k + 5], t6 = csr[k + 6], t7 = csr[k + 7];
    float p0 = __expf(lrelu(als[t0 * 4 + head] + ald));
    float p1 = __expf(lrelu(als[t1 * 4 + head] + ald));
    float p2 = __expf(lrelu(als[t2 * 4 + head] + ald));
    float p3 = __expf(lrelu(als[t3 * 4 + head] + ald));
    float p4 = __expf(lrelu(als[t4 * 4 + head] + ald));
    float p5 = __expf(lrelu(als[t5 * 4 + head] + ald));
    float p6 = __expf(lrelu(als[t6 * 4 + head] + ald));
    float p7 = __expf(lrelu(als[t7 * 4 + head] + ald));
    float4 r0 = *(const float4*)(hg + (size_t)t0 * 256 + l * 8);
    float4 r1 = *(const float4*)(hg + (size_t)t1 * 256 + l * 8);
    float4 r2 = *(const float4*)(hg + (size_t)t2 * 256 + l * 8);
    float4 r3 = *(const float4*)(hg + (size_t)t3 * 256 + l * 8);
    float4 r4 = *(const float4*)(hg + (size_t)t4 * 256 + l * 8);
    float4 r5 = *(const float4*)(hg + (size_t)t5 * 256 + l * 8);
    float4 r6 = *(const float4*)(hg + (size_t)t6 * 256 + l * 8);
    float4 r7 = *(const float4*)(hg + (size_t)t7 * 256 + l * 8);
    s += ((p0 + p1) + (p2 + p3)) + ((p4 + p5) + (p6 + p7));
    const __half2* h0 = (const __half2*)&r0;
    const __half2* h1 = (const __half2*)&r1;
    const __half2* h2 = (const __half2*)&r2;
    const __half2* h3 = (const __half2*)&r3;
    const __half2* h4 = (const __half2*)&r4;
    const __half2* h5 = (const __half2*)&r5;
    const __half2* h6 = (const __half2*)&r6;
    const __half2* h7 = (const __half2*)&r7;
#pragma unroll
    for (int i = 0; i < 4; ++i) {
      float2 f0 = __half22float2(h0[i]), f1 = __half22float2(h1[i]);
      float2 f2 = __half22float2(h2[i]), f3 = __half22float2(h3[i]);
      float2 f4 = __half22float2(h4[i]), f5 = __half22float2(h5[i]);
      float2 f6 = __half22float2(h6[i]), f7 = __half22float2(h7[i]);
      acc[2 * i]     += ((p0 * f0.x + p1 * f1.x) + (p2 * f2.x + p3 * f3.x)) +
                        ((p4 * f4.x + p5 * f5.x) + (p6 * f6.x + p7 * f7.x));
      acc[2 * i + 1] += ((p0 * f0.y + p1 * f1.y) + (p2 * f2.y + p3 * f3.y)) +
                        ((p4 * f4.y + p5 * f5.y) + (p6 * f6.y + p7 * f7.y));
    }
  }
  for (; k + 3 < end; k += 4) {
    int t0 = csr[k], t1 = csr[k + 1], t2 = csr[k + 2], t3 = csr[k + 3];
    float p0 = __expf(lrelu(als[t0 * 4 + head] + ald));
    float p1 = __expf(lrelu(als[t1 * 4 + head] + ald));
    float p2 = __expf(lrelu(als[t2 * 4 + head] + ald));
    float p3 = __expf(lrelu(als[t3 * 4 + head] + ald));
    float4 r0 = *(const float4*)(hg + (size_t)t0 * 256 + l * 8);
    float4 r1 = *(const float4*)(hg + (size_t)t1 * 256 + l * 8);
    float4 r2 = *(const float4*)(hg + (size_t)t2 * 256 + l * 8);
    float4 r3 = *(const float4*)(hg + (size_t)t3 * 256 + l * 8);
    s += (p0 + p1) + (p2 + p3);
    const __half2* h0 = (const __half2*)&r0;
    const __half2* h1 = (const __half2*)&r1;
    const __half2* h2 = (const __half2*)&r2;
    const __half2* h3 = (const __half2*)&r3;
#pragma unroll
    for (int i = 0; i < 4; ++i) {
      float2 f0 = __half22float2(h0[i]), f1 = __half22float2(h1[i]);
      float2 f2 = __half22float2(h2[i]), f3 = __half22float2(h3[i]);
      acc[2 * i]     += (p0 * f0.x + p1 * f1.x) + (p2 * f2.x + p3 * f3.x);
      acc[2 * i + 1] += (p0 * f0.y + p1 * f1.y) + (p2 * f2.y + p3 * f3.y);
    }
  }
  for (; k < end; ++k) {
    int src = csr[k];
    float pe = __expf(lrelu(als[src * 4 + head] + ald));
    float4 r0 = *(const float4*)(hg + (size_t)src * 256 + l * 8);
    const __half2* h0 = (const __half2*)&r0;
    s += pe;
#pragma unroll
    for (int i = 0; i < 4; ++i) {
      float2 f = __half22float2(h0[i]);
      acc[2 * i] += pe * f.x;
      acc[2 * i + 1] += pe * f.y;
    }
  }
  float inv = 1.f / s;
  float4 bb0 = *(const float4*)(b1 + l * 8);
  float4 bb1 = *(const float4*)(b1 + l * 8 + 4);
  unsigned short o[8];
#pragma unroll
  for (int i = 0; i < 8; ++i) {
    float b = (i < 4) ? (&bb0.x)[i] : (&bb1.x)[i - 4];
    o[i] = f2bf(lrelu(acc[i] * inv + b));
  }
  short4 w0 = make_short4((short)o[0], (short)o[1], (short)o[2], (short)o[3]);
  short4 w1 = make_short4((short)o[4], (short)o[5], (short)o[6], (short)o[7]);
  *(short4*)(A2 + (size_t)node * 256 + l * 8) = w0;
  *(short4*)(A2 + (size_t)node * 256 + l * 8 + 4) = w1;
}

// ---------------- layer-2 aggregation: 2 nodes/wave, batch-8 gathers --------
// 32 lanes per node; lane l owns channels l*4..l*4+3 (head l>>3).
__global__ __launch_bounds__(256) void gat_agg2(const __half* __restrict__ hg,
                                                const float* __restrict__ als,
                                                const float* __restrict__ aldv,
                                                const int* __restrict__ offs,
                                                const int* __restrict__ csr,
                                                const float* __restrict__ b2,
                                                float* __restrict__ out, int Nn) {
  int node = blockIdx.x * 8 + (threadIdx.x >> 5);
  if (node >= Nn) return;
  int l = threadIdx.x & 31;
  int head = l >> 3;
  float ald = aldv[node * 4 + head];
  float p = __expf(lrelu(als[node * 4 + head] + ald));
  float s = p;
  float acc[4];
  {
    float2 raw = *(const float2*)(hg + (size_t)node * 128 + l * 4);
    const __half2* hp = (const __half2*)&raw;
#pragma unroll
    for (int i = 0; i < 2; ++i) {
      float2 f = __half22float2(hp[i]);
      acc[2 * i] = p * f.x;
      acc[2 * i + 1] = p * f.y;
    }
  }
  int beg = offs[node], end = offs[node + 1];
  int k = beg;
  for (; k + 7 < end; k += 8) {
    int t0 = csr[k],     t1 = csr[k + 1], t2 = csr[k + 2], t3 = csr[k + 3];
    int t4 = csr[k + 4], t5 = csr[k + 5], t6 = csr[k + 6], t7 = csr[k + 7];
    float p0 = __expf(lrelu(als[t0 * 4 + head] + ald));
    float p1 = __expf(lrelu(als[t1 * 4 + head] + ald));
    float p2 = __expf(lrelu(als[t2 * 4 + head] + ald));
    float p3 = __expf(lrelu(als[t3 * 4 + head] + ald));
    float p4 = __expf(lrelu(als[t4 * 4 + head] + ald));
    float p5 = __expf(lrelu(als[t5 * 4 + head] + ald));
    float p6 = __expf(lrelu(als[t6 * 4 + head] + ald));
    float p7 = __expf(lrelu(als[t7 * 4 + head] + ald));
    float2 r0 = *(const float2*)(hg + (size_t)t0 * 128 + l * 4);
    float2 r1 = *(const float2*)(hg + (size_t)t1 * 128 + l * 4);
    float2 r2 = *(const float2*)(hg + (size_t)t2 * 128 + l * 4);
    float2 r3 = *(const float2*)(hg + (size_t)t3 * 128 + l * 4);
    float2 r4 = *(const float2*)(hg + (size_t)t4 * 128 + l * 4);
    float2 r5 = *(const float2*)(hg + (size_t)t5 * 128 + l * 4);
    float2 r6 = *(const float2*)(hg + (size_t)t6 * 128 + l * 4);
    float2 r7 = *(const float2*)(hg + (size_t)t7 * 128 + l * 4);
    s += ((p0 + p1) + (p2 + p3)) + ((p4 + p5) + (p6 + p7));
    const __half2* h0 = (const __half2*)&r0;
    const __half2* h1 = (const __half2*)&r1;
    const __half2* h2 = (const __half2*)&r2;
    const __half2* h3 = (const __half2*)&r3;
    const __half2* h4 = (const __half2*)&r4;
    const __half2* h5 = (const __half2*)&r5;
    const __half2* h6 = (const __half2*)&r6;
    const __half2* h7 = (const __half2*)&r7;
#pragma unroll
    for (int i = 0; i < 2; ++i) {
      float2 f0 = __half22float2(h0[i]), f1 = __half22float2(h1[i]);
      float2 f2 = __half22float2(h2[i]), f3 = __half22float2(h3[i]);
      float2 f4 = __half22float2(h4[i]), f5 = __half22float2(h5[i]);
      float2 f6 = __half22float2(h6[i]), f7 = __half22float2(h7[i]);
      acc[2 * i]     += ((p0 * f0.x + p1 * f1.x) + (p2 * f2.x + p3 * f3.x)) +
                        ((p4 * f4.x + p5 * f5.x) + (p6 * f6.x + p7 * f7.x));
      acc[2 * i + 1] += ((p0 * f0.y + p1 * f1.y) + (p2 * f2.y + p3 * f3.y)) +
                        ((p4 * f4.y + p5 * f5.y) + (p6 * f6.y + p7 * f7.y));
    }
  }
  for (; k + 3 < end; k += 4) {
    int t0 = csr[k], t1 = csr[k + 1], t2 = csr[k + 2], t3 = csr[k + 3];
    float p0 = __expf(lrelu(als[t0 * 4 + head] + ald));
    float p1 = __expf(lrelu(als[t1 * 4 + head] + ald));
    float p2 = __expf(lrelu(als[t2 * 4 + head] + ald));
    float p3 = __expf(lrelu(als[t3 * 4 + head] + ald));
    float2 r0 = *(const float2*)(hg + (size_t)t0 * 128 + l * 4);
    float2 r1 = *(const float2*)(hg + (size_t)t1 * 128 + l * 4);
    float2 r2 = *(const float2*)(hg + (size_t)t2 * 128 + l * 4);
    float2 r3 = *(const float2*)(hg + (size_t)t3 * 128 + l * 4);
    s += (p0 + p1) + (p2 + p3);
    const __half2* h0 = (const __half2*)&r0;
    const __half2* h1 = (const __half2*)&r1;
    const __half2* h2 = (const __half2*)&r2;
    const __half2* h3 = (const __half2*)&r3;
#pragma unroll
    for (int i = 0; i < 2; ++i) {
      float2 f0 = __half22float2(h0[i]), f1 = __half22float2(h1[i]);
      float2 f2 = __half22float2(h2[i]), f3 = __half22float2(h3[i]);
      acc[2 * i]     += (p0 * f0.x + p1 * f1.x) + (p2 * f2.x + p3 * f3.x);
      acc[2 * i + 1] += (p0 * f0.y + p1 * f1.y) + (p2 * f2.y + p3 * f3.y);
    }
  }
  for (; k < end; ++k) {
    int src = csr[k];
    float pe = __expf(lrelu(als[src * 4 + head] + ald));
    float2 r0 = *(const float2*)(hg + (size_t)src * 128 + l * 4);
    const __half2* h0 = (const __half2*)&r0;
    s += pe;
#pragma unroll
    for (int i = 0; i < 2; ++i) {
      float2 f = __half22float2(h0[i]);
      acc[2 * i] += pe * f.x;
      acc[2 * i + 1] += pe * f.y;
    }
  }
  float inv = 1.f / s;
  float v0 = acc[0] * inv, v1 = acc[1] * inv, v2 = acc[2] * inv, v3 = acc[3] * inv;
  // head mean: sum lanes l, l^8, l^16, l^24 (same channel slot, 4 heads)
  v0 += __shfl_xor(v0, 8, 64);  v0 += __shfl_xor(v0, 16, 64);
  v1 += __shfl_xor(v1, 8, 64);  v1 += __shfl_xor(v1, 16, 64);
  v2 += __shfl_xor(v2, 8, 64);  v2 += __shfl_xor(v2, 16, 64);
  v3 += __shfl_xor(v3, 8, 64);  v3 += __shfl_xor(v3, 16, 64);
  if (head == 0) {  // lanes 0..7 of each 32-lane group
    float4 bb = *(const float4*)(b2 + l * 4);
    float4 o;
    o.x = v0 * 0.25f + bb.x;
    o.y = v1 * 0.25f + bb.y;
    o.z = v2 * 0.25f + bb.z;
    o.w = v3 * 0.25f + bb.w;
    *(float4*)(out + (size_t)node * 32 + l * 4) = o;
  }
}

extern "C" void kernel_launch(void* const* d_in, const int* in_sizes, int n_in,
                              void* d_out, int out_size, void* d_ws, size_t ws_size,
                              hipStream_t stream) {
  const float* x   = (const float*)d_in[0];
  const int*   ei  = (const int*)d_in[1];
  const float* W1  = (const float*)d_in[2];
  const float* as1 = (const float*)d_in[3];
  const float* ad1 = (const float*)d_in[4];
  const float* b1  = (const float*)d_in[5];
  const float* W2  = (const float*)d_in[6];
  const float* as2 = (const float*)d_in[7];
  const float* ad2 = (const float*)d_in[8];
  const float* b2  = (const float*)d_in[9];
  float* out = (float*)d_out;

  const int CIN = 256, HD1 = 256, HD2 = 128;
  const int Nn = in_sizes[0] / CIN;   // 50000
  const int E  = in_sizes[1] / 2;     // 800000
  const int Mpad = (Nn + 127) & ~127; // 50048
  const int nchunk = (Nn + 255) / 256;  // 196 (fits single-block base scan <=256)

  char* p = (char*)d_ws;
  unsigned short* A12 = (unsigned short*)p; p += (size_t)Mpad * 256 * 2;  // bf16 A (x, then hact)
  __half* hg = (__half*)p; p += (size_t)Nn * 256 * 2;  // fp16 features (L1: 256-d, L2: 128-d)
  unsigned short* Bt1 = (unsigned short*)p; p += (size_t)256 * 512 * 2;
  unsigned short* Bt2 = (unsigned short*)p; p += (size_t)128 * 512 * 2;
  float* als1 = (float*)p; p += (size_t)Nn * 4 * 4;
  float* ald1 = (float*)p; p += (size_t)Nn * 4 * 4;
  float* als2 = (float*)p; p += (size_t)Nn * 4 * 4;
  float* ald2 = (float*)p; p += (size_t)Nn * 4 * 4;
  int* cnt   = (int*)p; p += (size_t)Nn * 4;
  int* offs  = (int*)p; p += (size_t)(Nn + 1) * 4;
  int* cur   = (int*)p; p += (size_t)Nn * 4;
  int* bsum  = (int*)p; p += (size_t)256 * 4;
  int* bbase = (int*)p; p += (size_t)256 * 4;
  int* csr   = (int*)p; p += (size_t)E * 4;

  const int* esrc = ei;
  const int* edst = ei + E;

  // ---- CSR build (hierarchical scan) ----
  hipMemsetAsync(cnt, 0, (size_t)Nn * sizeof(int), stream);
  hist_kernel<<<2048, 256, 0, stream>>>(edst, cnt, E);
  chunk_sum_kernel<<<nchunk, 256, 0, stream>>>(cnt, bsum, Nn);
  scan_base_kernel<<<1, 256, 0, stream>>>(bsum, bbase, offs, nchunk, Nn);
  chunk_scan_kernel<<<nchunk, 256, 0, stream>>>(cnt, bbase, offs, cur, Nn);
  scatter_kernel<<<2048, 256, 0, stream>>>(esrc, edst, cur, csr, E);

  // ---- operand prep (pad zero-fill folded into split_x) ----
  split_x_kernel<<<2048, 256, 0, stream>>>(x, A12, Nn, Mpad);
  build_bt_kernel<<<384, 256, 0, stream>>>(W1, W2, Bt1, Bt2);

  // ---- layer 1 (GEMM + fused logits) ----
  gemm_fused<6><<<dim3(HD1 / 128, Mpad / 128), 256, 0, stream>>>(
      A12, Bt1, as1, ad1, hg, als1, ald1, Nn, HD1);
  gat_agg1<<<(Nn + 7) / 8, 256, 0, stream>>>(hg, als1, ald1, offs, csr, b1, A12, Nn);

  // ---- layer 2 (GEMM + fused logits) ----
  gemm_fused<5><<<dim3(HD2 / 128, Mpad / 128), 256, 0, stream>>>(
      A12, Bt2, as2, ad2, hg, als2, ald2, Nn, HD2);
  gat_agg2<<<(Nn + 7) / 8, 256, 0, stream>>>(hg, als2, ald2, offs, csr, b2, out, Nn);
}

// Round 16
// 258.410 us; speedup vs baseline: 1.0573x; 1.0573x over previous
//
#include <hip/hip_runtime.h>
#include <hip/hip_fp16.h>

#define NEG_SLOPE_F 0.2f

typedef __attribute__((ext_vector_type(8))) short bf16x8;
typedef __attribute__((ext_vector_type(4))) float f32x4;

__device__ __forceinline__ float lrelu(float v) { return v > 0.0f ? v : NEG_SLOPE_F * v; }

__device__ __forceinline__ unsigned short f2bf(float f) {
  unsigned int u = __float_as_uint(f);
  u += 0x7FFFu + ((u >> 16) & 1u);  // round-to-nearest-even
  return (unsigned short)(u >> 16);
}
__device__ __forceinline__ float bf2f(unsigned short s) {
  return __uint_as_float(((unsigned int)s) << 16);
}

// ---------------- fused prep: hist + split_x + build_bt (independent) -------
// blocks [0,1024): histogram of dst; [1024,2048): x->bf16; [2048,2432): Bt.
__global__ void fused_prep_kernel(const int* __restrict__ dst, int* __restrict__ cnt, int E,
                                  const float* __restrict__ x, unsigned short* __restrict__ A12,
                                  int rows, int rowsPad,
                                  const float* __restrict__ W1, const float* __restrict__ W2,
                                  unsigned short* __restrict__ Bt1, unsigned short* __restrict__ Bt2) {
  int b = blockIdx.x;
  if (b < 1024) {
    for (int i = b * 256 + threadIdx.x; i < E; i += 1024 * 256)
      atomicAdd(&cnt[dst[i]], 1);
  } else if (b < 2048) {
    int total = rowsPad * 64;  // groups of 4 elems
    for (int i = (b - 1024) * 256 + threadIdx.x; i < total; i += 1024 * 256) {
      int r = i >> 6, c = (i & 63) * 4;
      short4 hv;
      if (r < rows) {
        float4 v = *(const float4*)(x + (size_t)r * 256 + c);
        hv = make_short4((short)f2bf(v.x), (short)f2bf(v.y),
                         (short)f2bf(v.z), (short)f2bf(v.w));
      } else {
        hv = make_short4(0, 0, 0, 0);
      }
      *(short4*)(A12 + (size_t)r * 256 + c) = hv;
    }
  } else {
    int i = (b - 2048) * 256 + threadIdx.x;
    const int total1 = 256 * 256;
    const int total2 = 128 * 256;
    if (i < total1) {
      int n = i >> 8, k = i & 255;
      float v = W1[(size_t)k * 256 + n];
      unsigned short hi = f2bf(v);
      unsigned short lo = f2bf(v - bf2f(hi));
      Bt1[(size_t)n * 512 + k] = hi;
      Bt1[(size_t)n * 512 + 256 + k] = lo;
    } else if (i < total1 + total2) {
      int j = i - total1;
      int n = j >> 8, k = j & 255;
      float v = W2[(size_t)k * 128 + n];
      unsigned short hi = f2bf(v);
      unsigned short lo = f2bf(v - bf2f(hi));
      Bt2[(size_t)n * 512 + k] = hi;
      Bt2[(size_t)n * 512 + 256 + k] = lo;
    }
  }
}

// ---------------- CSR scan + scatter ----------------
__global__ void chunk_sum_kernel(const int* __restrict__ cnt, int* __restrict__ bsum, int Nn) {
  __shared__ int sm[256];
  int t = threadIdx.x;
  int i = blockIdx.x * 256 + t;
  sm[t] = (i < Nn) ? cnt[i] : 0;
  __syncthreads();
  for (int off = 128; off > 0; off >>= 1) {
    if (t < off) sm[t] += sm[t + off];
    __syncthreads();
  }
  if (t == 0) bsum[blockIdx.x] = sm[0];
}

__global__ void scan_base_kernel(const int* __restrict__ bsum, int* __restrict__ bbase,
                                 int* __restrict__ offs, int nchunk, int Nn) {
  __shared__ int sm[256];
  int t = threadIdx.x;
  int v = (t < nchunk) ? bsum[t] : 0;
  sm[t] = v;
  __syncthreads();
  for (int off = 1; off < 256; off <<= 1) {
    int x = (t >= off) ? sm[t - off] : 0;
    __syncthreads();
    sm[t] += x;
    __syncthreads();
  }
  if (t < nchunk) bbase[t] = sm[t] - v;  // exclusive base for chunk t
  if (t == 255) offs[Nn] = sm[255];      // grand total
}

__global__ void chunk_scan_kernel(const int* __restrict__ cnt, const int* __restrict__ bbase,
                                  int* __restrict__ offs, int* __restrict__ cur, int Nn) {
  __shared__ int sm[256];
  int t = threadIdx.x;
  int i = blockIdx.x * 256 + t;
  int v = (i < Nn) ? cnt[i] : 0;
  sm[t] = v;
  __syncthreads();
  for (int off = 1; off < 256; off <<= 1) {
    int x = (t >= off) ? sm[t - off] : 0;
    __syncthreads();
    sm[t] += x;
    __syncthreads();
  }
  if (i < Nn) {
    int ex = bbase[blockIdx.x] + sm[t] - v;
    offs[i] = ex;
    cur[i] = ex;
  }
}

__global__ void scatter_kernel(const int* __restrict__ src, const int* __restrict__ dst,
                               int* __restrict__ cur, int* __restrict__ csr, int E) {
  for (int i = blockIdx.x * blockDim.x + threadIdx.x; i < E; i += gridDim.x * blockDim.x) {
    int p = atomicAdd(&cur[dst[i]], 1);
    csr[p] = src[i];
  }
}

// ---------------- bf16 MFMA GEMM (C = A x (B_hi+B_lo)), single-pass A -------
// A[Mpad,256] bf16, Bt[N,512] (hi|lo). 8 K-tiles of 32; per tile stage A once
// plus BOTH B parts, two MFMA sets per barrier pair. Fused logit epilogue.
// DLOG = log2(head dim): 6 (L1, D=64), 5 (L2, D=32).
template <int DLOG>
__global__ __launch_bounds__(256) void gemm_fused(const unsigned short* __restrict__ A,
                                                  const unsigned short* __restrict__ Bt,
                                                  const float* __restrict__ a_src,
                                                  const float* __restrict__ a_dst,
                                                  __half* __restrict__ Ch,
                                                  float* __restrict__ al_s,
                                                  float* __restrict__ al_d,
                                                  int M, int N) {
  __shared__ unsigned short As[128 * 32];
  __shared__ unsigned short Bs[2 * 128 * 32];  // [part][row][slot]
  const int tid = threadIdx.x;
  const int lane = tid & 63;
  const int wave = tid >> 6;
  const int wm = (wave >> 1) * 64;
  const int wn = (wave & 1) * 64;
  const int bm = blockIdx.y * 128;
  const int bn = blockIdx.x * 128;
  const int fr = lane & 15;
  const int q = lane >> 4;
  const int srow = tid >> 2;   // 0..63
  const int sslot = tid & 3;
  f32x4 acc[4][4] = {};
  for (int kt = 0; kt < 8; ++kt) {
    const int kk = kt * 32;
#pragma unroll
    for (int i = 0; i < 2; ++i) {
      int r = i * 64 + srow;
      int sl = sslot ^ (r & 3);
      __builtin_amdgcn_global_load_lds(
          (const __attribute__((address_space(1))) unsigned int*)(A + (size_t)(bm + r) * 256 + kk + sl * 8),
          (__attribute__((address_space(3))) unsigned int*)((char*)As + i * 4096 + wave * 1024),
          16, 0, 0);
    }
#pragma unroll
    for (int pp = 0; pp < 2; ++pp) {
#pragma unroll
      for (int i = 0; i < 2; ++i) {
        int r = i * 64 + srow;
        int sl = sslot ^ (r & 3);
        __builtin_amdgcn_global_load_lds(
            (const __attribute__((address_space(1))) unsigned int*)(Bt + (size_t)(bn + r) * 512 + pp * 256 + kk + sl * 8),
            (__attribute__((address_space(3))) unsigned int*)((char*)Bs + pp * 8192 + i * 4096 + wave * 1024),
            16, 0, 0);
      }
    }
    __syncthreads();  // drains vmcnt -> LDS tiles ready
    bf16x8 af[4], bh[4], bl[4];
#pragma unroll
    for (int mi = 0; mi < 4; ++mi) {
      int r = wm + mi * 16 + fr;
      af[mi] = *(const bf16x8*)(As + r * 32 + (q ^ (r & 3)) * 8);
    }
#pragma unroll
    for (int ni = 0; ni < 4; ++ni) {
      int r = wn + ni * 16 + fr;
      bh[ni] = *(const bf16x8*)(Bs + r * 32 + (q ^ (r & 3)) * 8);
      bl[ni] = *(const bf16x8*)(Bs + 4096 + r * 32 + (q ^ (r & 3)) * 8);
    }
#pragma unroll
    for (int mi = 0; mi < 4; ++mi)
#pragma unroll
      for (int ni = 0; ni < 4; ++ni) {
        acc[mi][ni] = __builtin_amdgcn_mfma_f32_16x16x32_bf16(af[mi], bh[ni], acc[mi][ni], 0, 0, 0);
        acc[mi][ni] = __builtin_amdgcn_mfma_f32_16x16x32_bf16(af[mi], bl[ni], acc[mi][ni], 0, 0, 0);
      }
    __syncthreads();  // compute done before next-stage overwrite
  }
  // attention vectors for this thread's 4 columns (flat index == col)
  float asv[4], adv[4];
#pragma unroll
  for (int ni = 0; ni < 4; ++ni) {
    int colg = bn + wn + ni * 16 + fr;
    asv[ni] = a_src[colg];
    adv[ni] = a_dst[colg];
  }
  const int hb = (bn + wn) >> DLOG;
#pragma unroll
  for (int mi = 0; mi < 4; ++mi) {
#pragma unroll
    for (int r = 0; r < 4; ++r) {
      int row = bm + wm + mi * 16 + q * 4 + r;
      float ps0 = 0.f, pd0 = 0.f, ps1 = 0.f, pd1 = 0.f;
#pragma unroll
      for (int ni = 0; ni < 4; ++ni) {
        float v = acc[mi][ni][r];
        if (DLOG == 6 || ni < 2) { ps0 += v * asv[ni]; pd0 += v * adv[ni]; }
        else                     { ps1 += v * asv[ni]; pd1 += v * adv[ni]; }
      }
#pragma unroll
      for (int off = 1; off < 16; off <<= 1) {
        ps0 += __shfl_xor(ps0, off, 64);
        pd0 += __shfl_xor(pd0, off, 64);
        if (DLOG == 5) {
          ps1 += __shfl_xor(ps1, off, 64);
          pd1 += __shfl_xor(pd1, off, 64);
        }
      }
      if (fr == 0 && row < M) {
        al_s[row * 4 + hb] = ps0;
        al_d[row * 4 + hb] = pd0;
        if (DLOG == 5) {
          al_s[row * 4 + hb + 1] = ps1;
          al_d[row * 4 + hb + 1] = pd1;
        }
      }
    }
  }
  // fp16 feature store
#pragma unroll
  for (int mi = 0; mi < 4; ++mi) {
#pragma unroll
    for (int ni = 0; ni < 4; ++ni) {
      int col = bn + wn + ni * 16 + fr;
#pragma unroll
      for (int r = 0; r < 4; ++r) {
        int row = bm + wm + mi * 16 + q * 4 + r;
        if (row < M) Ch[(size_t)row * N + col] = __float2half(acc[mi][ni][r]);
      }
    }
  }
}

// ---------------- layer-1 aggregation: 2 nodes/wave, batch-4 gathers --------
// 32 lanes per node; lane l owns channels l*8..l*8+7 (head l>>3).
__global__ __launch_bounds__(256) void gat_agg1(const __half* __restrict__ hg,
                                                const float* __restrict__ als,
                                                const float* __restrict__ aldv,
                                                const int* __restrict__ offs,
                                                const int* __restrict__ csr,
                                                const float* __restrict__ b1,
                                                unsigned short* __restrict__ A2, int Nn) {
  int node = blockIdx.x * 8 + (threadIdx.x >> 5);
  if (node >= Nn) return;
  int l = threadIdx.x & 31;
  int head = l >> 3;
  float ald = aldv[node * 4 + head];
  float p = __expf(lrelu(als[node * 4 + head] + ald));  // self-loop
  float s = p;
  float acc[8];
  {
    float4 raw = *(const float4*)(hg + (size_t)node * 256 + l * 8);
    const __half2* hp = (const __half2*)&raw;
#pragma unroll
    for (int i = 0; i < 4; ++i) {
      float2 f = __half22float2(hp[i]);
      acc[2 * i] = p * f.x;
      acc[2 * i + 1] = p * f.y;
    }
  }
  int beg = offs[node], end = offs[node + 1];
  int k = beg;
  for (; k + 3 < end; k += 4) {
    int t0 = csr[k], t1 = csr[k + 1], t2 = csr[k + 2], t3 = csr[k + 3];
    float p0 = __expf(lrelu(als[t0 * 4 + head] + ald));
    float p1 = __expf(lrelu(als[t1 * 4 + head] + ald));
    float p2 = __expf(lrelu(als[t2 * 4 + head] + ald));
    float p3 = __expf(lrelu(als[t3 * 4 + head] + ald));
    float4 r0 = *(const float4*)(hg + (size_t)t0 * 256 + l * 8);
    float4 r1 = *(const float4*)(hg + (size_t)t1 * 256 + l * 8);
    float4 r2 = *(const float4*)(hg + (size_t)t2 * 256 + l * 8);
    float4 r3 = *(const float4*)(hg + (size_t)t3 * 256 + l * 8);
    s += (p0 + p1) + (p2 + p3);
    const __half2* h0 = (const __half2*)&r0;
    const __half2* h1 = (const __half2*)&r1;
    const __half2* h2 = (const __half2*)&r2;
    const __half2* h3 = (const __half2*)&r3;
#pragma unroll
    for (int i = 0; i < 4; ++i) {
      float2 f0 = __half22float2(h0[i]), f1 = __half22float2(h1[i]);
      float2 f2 = __half22float2(h2[i]), f3 = __half22float2(h3[i]);
      acc[2 * i]     += (p0 * f0.x + p1 * f1.x) + (p2 * f2.x + p3 * f3.x);
      acc[2 * i + 1] += (p0 * f0.y + p1 * f1.y) + (p2 * f2.y + p3 * f3.y);
    }
  }
  for (; k < end; ++k) {
    int src = csr[k];
    float pe = __expf(lrelu(als[src * 4 + head] + ald));
    float4 r0 = *(const float4*)(hg + (size_t)src * 256 + l * 8);
    const __half2* h0 = (const __half2*)&r0;
    s += pe;
#pragma unroll
    for (int i = 0; i < 4; ++i) {
      float2 f = __half22float2(h0[i]);
      acc[2 * i] += pe * f.x;
      acc[2 * i + 1] += pe * f.y;
    }
  }
  float inv = 1.f / s;
  float4 bb0 = *(const float4*)(b1 + l * 8);
  float4 bb1 = *(const float4*)(b1 + l * 8 + 4);
  unsigned short o[8];
#pragma unroll
  for (int i = 0; i < 8; ++i) {
    float b = (i < 4) ? (&bb0.x)[i] : (&bb1.x)[i - 4];
    o[i] = f2bf(lrelu(acc[i] * inv + b));
  }
  short4 w0 = make_short4((short)o[0], (short)o[1], (short)o[2], (short)o[3]);
  short4 w1 = make_short4((short)o[4], (short)o[5], (short)o[6], (short)o[7]);
  *(short4*)(A2 + (size_t)node * 256 + l * 8) = w0;
  *(short4*)(A2 + (size_t)node * 256 + l * 8 + 4) = w1;
}

// ---------------- layer-2 aggregation: 2 nodes/wave, batch-4 gathers --------
// 32 lanes per node; lane l owns channels l*4..l*4+3 (head l>>3).
__global__ __launch_bounds__(256) void gat_agg2(const __half* __restrict__ hg,
                                                const float* __restrict__ als,
                                                const float* __restrict__ aldv,
                                                const int* __restrict__ offs,
                                                const int* __restrict__ csr,
                                                const float* __restrict__ b2,
                                                float* __restrict__ out, int Nn) {
  int node = blockIdx.x * 8 + (threadIdx.x >> 5);
  if (node >= Nn) return;
  int l = threadIdx.x & 31;
  int head = l >> 3;
  float ald = aldv[node * 4 + head];
  float p = __expf(lrelu(als[node * 4 + head] + ald));
  float s = p;
  float acc[4];
  {
    float2 raw = *(const float2*)(hg + (size_t)node * 128 + l * 4);
    const __half2* hp = (const __half2*)&raw;
#pragma unroll
    for (int i = 0; i < 2; ++i) {
      float2 f = __half22float2(hp[i]);
      acc[2 * i] = p * f.x;
      acc[2 * i + 1] = p * f.y;
    }
  }
  int beg = offs[node], end = offs[node + 1];
  int k = beg;
  for (; k + 3 < end; k += 4) {
    int s0 = csr[k], s1 = csr[k + 1], s2 = csr[k + 2], s3 = csr[k + 3];
    float p0 = __expf(lrelu(als[s0 * 4 + head] + ald));
    float p1 = __expf(lrelu(als[s1 * 4 + head] + ald));
    float p2 = __expf(lrelu(als[s2 * 4 + head] + ald));
    float p3 = __expf(lrelu(als[s3 * 4 + head] + ald));
    float2 r0 = *(const float2*)(hg + (size_t)s0 * 128 + l * 4);
    float2 r1 = *(const float2*)(hg + (size_t)s1 * 128 + l * 4);
    float2 r2 = *(const float2*)(hg + (size_t)s2 * 128 + l * 4);
    float2 r3 = *(const float2*)(hg + (size_t)s3 * 128 + l * 4);
    s += (p0 + p1) + (p2 + p3);
    const __half2* h0 = (const __half2*)&r0;
    const __half2* h1 = (const __half2*)&r1;
    const __half2* h2 = (const __half2*)&r2;
    const __half2* h3 = (const __half2*)&r3;
#pragma unroll
    for (int i = 0; i < 2; ++i) {
      float2 f0 = __half22float2(h0[i]), f1 = __half22float2(h1[i]);
      float2 f2 = __half22float2(h2[i]), f3 = __half22float2(h3[i]);
      acc[2 * i]     += (p0 * f0.x + p1 * f1.x) + (p2 * f2.x + p3 * f3.x);
      acc[2 * i + 1] += (p0 * f0.y + p1 * f1.y) + (p2 * f2.y + p3 * f3.y);
    }
  }
  for (; k < end; ++k) {
    int src = csr[k];
    float pe = __expf(lrelu(als[src * 4 + head] + ald));
    float2 r0 = *(const float2*)(hg + (size_t)src * 128 + l * 4);
    const __half2* h0 = (const __half2*)&r0;
    s += pe;
#pragma unroll
    for (int i = 0; i < 2; ++i) {
      float2 f = __half22float2(h0[i]);
      acc[2 * i] += pe * f.x;
      acc[2 * i + 1] += pe * f.y;
    }
  }
  float inv = 1.f / s;
  float v0 = acc[0] * inv, v1 = acc[1] * inv, v2 = acc[2] * inv, v3 = acc[3] * inv;
  // head mean: sum lanes l, l^8, l^16, l^24 (same channel slot, 4 heads)
  v0 += __shfl_xor(v0, 8, 64);  v0 += __shfl_xor(v0, 16, 64);
  v1 += __shfl_xor(v1, 8, 64);  v1 += __shfl_xor(v1, 16, 64);
  v2 += __shfl_xor(v2, 8, 64);  v2 += __shfl_xor(v2, 16, 64);
  v3 += __shfl_xor(v3, 8, 64);  v3 += __shfl_xor(v3, 16, 64);
  if (head == 0) {  // lanes 0..7 of each 32-lane group
    float4 bb = *(const float4*)(b2 + l * 4);
    float4 o;
    o.x = v0 * 0.25f + bb.x;
    o.y = v1 * 0.25f + bb.y;
    o.z = v2 * 0.25f + bb.z;
    o.w = v3 * 0.25f + bb.w;
    *(float4*)(out + (size_t)node * 32 + l * 4) = o;
  }
}

extern "C" void kernel_launch(void* const* d_in, const int* in_sizes, int n_in,
                              void* d_out, int out_size, void* d_ws, size_t ws_size,
                              hipStream_t stream) {
  const float* x   = (const float*)d_in[0];
  const int*   ei  = (const int*)d_in[1];
  const float* W1  = (const float*)d_in[2];
  const float* as1 = (const float*)d_in[3];
  const float* ad1 = (const float*)d_in[4];
  const float* b1  = (const float*)d_in[5];
  const float* W2  = (const float*)d_in[6];
  const float* as2 = (const float*)d_in[7];
  const float* ad2 = (const float*)d_in[8];
  const float* b2  = (const float*)d_in[9];
  float* out = (float*)d_out;

  const int CIN = 256, HD1 = 256, HD2 = 128;
  const int Nn = in_sizes[0] / CIN;   // 50000
  const int E  = in_sizes[1] / 2;     // 800000
  const int Mpad = (Nn + 127) & ~127; // 50048
  const int nchunk = (Nn + 255) / 256;  // 196 (fits single-block base scan <=256)

  char* p = (char*)d_ws;
  unsigned short* A12 = (unsigned short*)p; p += (size_t)Mpad * 256 * 2;  // bf16 A (x, then hact)
  __half* hg = (__half*)p; p += (size_t)Nn * 256 * 2;  // fp16 features (L1: 256-d, L2: 128-d)
  unsigned short* Bt1 = (unsigned short*)p; p += (size_t)256 * 512 * 2;
  unsigned short* Bt2 = (unsigned short*)p; p += (size_t)128 * 512 * 2;
  float* als1 = (float*)p; p += (size_t)Nn * 4 * 4;
  float* ald1 = (float*)p; p += (size_t)Nn * 4 * 4;
  float* als2 = (float*)p; p += (size_t)Nn * 4 * 4;
  float* ald2 = (float*)p; p += (size_t)Nn * 4 * 4;
  int* cnt   = (int*)p; p += (size_t)Nn * 4;
  int* offs  = (int*)p; p += (size_t)(Nn + 1) * 4;
  int* cur   = (int*)p; p += (size_t)Nn * 4;
  int* bsum  = (int*)p; p += (size_t)256 * 4;
  int* bbase = (int*)p; p += (size_t)256 * 4;
  int* csr   = (int*)p; p += (size_t)E * 4;

  const int* esrc = ei;
  const int* edst = ei + E;

  // ---- fused prep: hist + x->bf16 + weight split (one launch) ----
  hipMemsetAsync(cnt, 0, (size_t)Nn * sizeof(int), stream);
  fused_prep_kernel<<<2432, 256, 0, stream>>>(edst, cnt, E, x, A12, Nn, Mpad,
                                              W1, W2, Bt1, Bt2);

  // ---- CSR scan + scatter ----
  chunk_sum_kernel<<<nchunk, 256, 0, stream>>>(cnt, bsum, Nn);
  scan_base_kernel<<<1, 256, 0, stream>>>(bsum, bbase, offs, nchunk, Nn);
  chunk_scan_kernel<<<nchunk, 256, 0, stream>>>(cnt, bbase, offs, cur, Nn);
  scatter_kernel<<<2048, 256, 0, stream>>>(esrc, edst, cur, csr, E);

  // ---- layer 1 (GEMM + fused logits) ----
  gemm_fused<6><<<dim3(HD1 / 128, Mpad / 128), 256, 0, stream>>>(
      A12, Bt1, as1, ad1, hg, als1, ald1, Nn, HD1);
  gat_agg1<<<(Nn + 7) / 8, 256, 0, stream>>>(hg, als1, ald1, offs, csr, b1, A12, Nn);

  // ---- layer 2 (GEMM + fused logits) ----
  gemm_fused<5><<<dim3(HD2 / 128, Mpad / 128), 256, 0, stream>>>(
      A12, Bt2, as2, ad2, hg, als2, ald2, Nn, HD2);
  gat_agg2<<<(Nn + 7) / 8, 256, 0, stream>>>(hg, als2, ald2, offs, csr, b2, out, Nn);
}